// Round 9
// baseline (53.600 us; speedup 1.0000x reference)
//
#include <hip/hip_runtime.h>
#include <stdint.h>

#define BROWS 16384
#define CDIM  4096
#define NCLS  64
#define BLKLEN 819u
#define NWAVES 8
#define MROWS 16                  // rows per block
#define CH 256                    // block K-step per chunk (floats); wave slice = 32
#define NCHUNK (CDIM / CH)        // 16

typedef __attribute__((ext_vector_type(4))) float f32x4;
typedef __attribute__((ext_vector_type(2))) float f32x2;
typedef __attribute__((ext_vector_type(8))) short s16x8;   // 8 bf16 - MFMA A/B frag

// fp32 -> bf16 bits, round-to-nearest-even
static __device__ __forceinline__ unsigned short f2bf(float f) {
    union { float f; unsigned u; } v; v.f = f;
    unsigned u = v.u;
    u += 0x7FFFu + ((u >> 16) & 1u);
    return (unsigned short)(u >> 16);
}

static __device__ __forceinline__ void gload_lds16(const void* g, void* l) {
    __builtin_amdgcn_global_load_lds(
        (const __attribute__((address_space(1))) unsigned int*)g,
        (__attribute__((address_space(3))) unsigned int*)l,
        16, 0, 0);
}

// One-time W relayout to FRAGMENT-MAJOR bf16:
// unit u = (kk*4 + t)*64 + lane (16B each) holds bf16x8 of
//   W[t*16 + (lane&15)][kk*32 + (lane>>4)*8 .. +8)
__global__ __launch_bounds__(256) void convert_w_fragmajor(const float* __restrict__ W,
                                                           unsigned short* __restrict__ Wfm) {
    const int u    = blockIdx.x * 256 + threadIdx.x;   // 0..32767
    const int lane = u & 63;
    const int t    = (u >> 6) & 3;
    const int kk   = u >> 8;
    const int row  = t * 16 + (lane & 15);
    const int col  = kk * 32 + (lane >> 4) * 8;
    const float* p = W + (size_t)row * CDIM + col;
    f32x4 a = *reinterpret_cast<const f32x4*>(p);
    f32x4 b = *reinterpret_cast<const f32x4*>(p + 4);
    s16x8 o;
    #pragma unroll
    for (int j = 0; j < 4; ++j) {
        o[j]     = (short)f2bf(a[j]);
        o[j + 4] = (short)f2bf(b[j]);
    }
    *reinterpret_cast<s16x8*>(Wfm + (size_t)u * 8) = o;
}

// Masked skinny GEMM: out[16384,64] = mask(x) @ W^T + b
// Block = 16 rows x 8 waves (512 thr), split-K (wave wv owns cols
// ch*256 + wv*32 of each chunk). DEPTH-2 wave-private LDS staging
// (2KB x 3 buffers/wave) + reg-prefetched W (depth-1) + counted vmcnt.
// Masked-window stage lanes address-clamped (static instr count; ~19% less
// x traffic). No __syncthreads in the main loop.
template<bool PRECONV>
__global__ __launch_bounds__(512, 4) void dropblock_gemm_kernel(
    const float* __restrict__ x,
    const float* __restrict__ Wf,            // fp32 W (fallback)
    const unsigned short* __restrict__ Wfm,  // frag-major bf16 W
    const float* __restrict__ bias,
    const int* __restrict__ starts,
    float* __restrict__ out)
{
    __shared__ float lds[NWAVES][3][MROWS][32]; // 48 KB; 6 KB private per wave
    const int tid  = threadIdx.x;
    const int lane = tid & 63;
    const int wv   = tid >> 6;               // wave 0..7 -> K-slice
    const int l16  = lane & 15;
    const int lg   = lane >> 4;              // 0..3
    const int row_base = blockIdx.x * MROWS;

    const int s0 = starts[row_base + l16];
    // starts for this lane's STAGE rows r = i*8 + (lane>>3), i=0..1
    int sr[2];
    #pragma unroll
    for (int i = 0; i < 2; ++i) sr[i] = starts[row_base + i * 8 + (lane >> 3)];

    const unsigned swzA = (unsigned)((l16 & 7) << 4);
    char* mybuf = (char*)&lds[wv][0][0][0];

    f32x4 acc[4];
    #pragma unroll
    for (int t = 0; t < 4; ++t) acc[t] = (f32x4){0.f, 0.f, 0.f, 0.f};

    // Stage chunk ch (this wave's 16x32 f32 subtile) into private buffer bi.
    // LDS linear 16B unit u = i*64+lane -> row r = i*8+(lane>>3), slot lane&7;
    // source pre-swizzled by ((r&7)<<4) so reads XOR the same involution.
    // Fully-masked units clamp to one shared line (keeps vmcnt count static).
    auto stage = [&](int ch, int bi) {
        char* lb = mybuf + bi * 2048;
        const size_t colbase = (size_t)ch * CH + (size_t)wv * 32;
        const char* gclamp = (const char*)x + ((size_t)row_base * CDIM + colbase) * 4;
        #pragma unroll
        for (int i = 0; i < 2; ++i) {
            const int r = i * 8 + (lane >> 3);
            const unsigned wb = ((unsigned)((lane & 7) * 16)) ^ ((unsigned)((r & 7) << 4));
            const int c0 = (int)colbase + (int)(wb >> 2);
            const bool fullmask = (unsigned)(c0 - sr[i]) <= (BLKLEN - 4u);
            const char* gnorm = (const char*)x
                + ((size_t)(row_base + r) * CDIM + colbase) * 4 + wb;
            const char* g = fullmask ? gclamp : gnorm;
            gload_lds16(g, lb + i * 1024);
        }
    };

    s16x8 wfr[2][4];                          // W frag double-buffer
    auto loadW = [&](int ch, int bi) {
        const int kk = ch * 8 + wv;           // global k0/32 index for this wave
        #pragma unroll
        for (int t = 0; t < 4; ++t)
            wfr[bi][t] = *reinterpret_cast<const s16x8*>(
                Wfm + ((size_t)((kk * 4 + t) * 64 + lane)) * 8);
    };

    // Prologue (issue order matters for the in-order vmcnt discipline):
    stage(0, 0);
    if (PRECONV) loadW(0, 0);
    stage(1, 1);

    #pragma unroll
    for (int ch = 0; ch < NCHUNK; ++ch) {
        if (PRECONV && ch + 1 < NCHUNK) loadW(ch + 1, (ch + 1) & 1);
        if (ch + 2 < NCHUNK) stage(ch + 2, (ch + 2) % 3);

        __builtin_amdgcn_sched_barrier(0);
        if (PRECONV) {
            // steady state: drain stage(ch)+W(ch); leave stage(ch+1)[2] +
            // W(ch+1)[4] + stage(ch+2)[2] = 8 outstanding.
            if (ch + 2 < NCHUNK)      asm volatile("s_waitcnt vmcnt(8)" ::: "memory");
            else if (ch + 1 < NCHUNK) asm volatile("s_waitcnt vmcnt(6)" ::: "memory");
            else                      asm volatile("s_waitcnt vmcnt(0)" ::: "memory");
        } else {
            asm volatile("s_waitcnt vmcnt(0)" ::: "memory");   // conservative fallback
        }
        __builtin_amdgcn_sched_barrier(0);

        const char* lb = mybuf + (ch % 3) * 2048;
        const unsigned a0 = (unsigned)(l16 * 128 + lg * 32);
        f32x4 xa = *reinterpret_cast<const f32x4*>(lb + (a0 ^ swzA));
        f32x4 xb = *reinterpret_cast<const f32x4*>(lb + ((a0 + 16) ^ swzA));

        const int d0 = ch * CH + wv * 32 + lg * 8 - s0;
        s16x8 afrag;
        #pragma unroll
        for (int j = 0; j < 4; ++j) {
            float va = ((unsigned)(d0 + j)     >= BLKLEN) ? xa[j] : 0.f;
            float vb = ((unsigned)(d0 + 4 + j) >= BLKLEN) ? xb[j] : 0.f;
            afrag[j]     = (short)f2bf(va);
            afrag[j + 4] = (short)f2bf(vb);
        }

        #pragma unroll
        for (int t = 0; t < 4; ++t) {
            s16x8 bfrag;
            if (PRECONV) {
                bfrag = wfr[ch & 1][t];
            } else {
                const int kk = ch * 8 + wv;
                const float* wrow = Wf + (size_t)(t * 16 + l16) * CDIM + kk * 32 + lg * 8;
                f32x4 wa = *reinterpret_cast<const f32x4*>(wrow);
                f32x4 wb2 = *reinterpret_cast<const f32x4*>(wrow + 4);
                #pragma unroll
                for (int j = 0; j < 4; ++j) {
                    bfrag[j]     = (short)f2bf(wa[j]);
                    bfrag[j + 4] = (short)f2bf(wb2[j]);
                }
            }
            acc[t] = __builtin_amdgcn_mfma_f32_16x16x32_bf16(afrag, bfrag, acc[t], 0, 0, 0);
        }
    }

    // Partials: plds aliases the stage buffers across waves -> barrier BEFORE
    // writing (other waves may still read their own staging), then after.
    __syncthreads();
    float (*plds)[MROWS][64] = reinterpret_cast<float (*)[MROWS][64]>(&lds[0][0][0][0]); // 32 KB
    #pragma unroll
    for (int t = 0; t < 4; ++t)
        #pragma unroll
        for (int i = 0; i < 4; ++i)
            plds[wv][lg * 4 + i][t * 16 + l16] = acc[t][i];
    __syncthreads();

    // Reduce 8 partials + bias. 512 threads x f32x2 = 1024 outputs.
    const int row  = tid >> 5;               // 0..15
    const int col2 = (tid & 31) * 2;         // 0,2,..,62
    f32x2 sum = (f32x2){bias[col2], bias[col2 + 1]};
    #pragma unroll
    for (int w = 0; w < NWAVES; ++w) {
        f32x2 p = *reinterpret_cast<const f32x2*>(&plds[w][row][col2]);
        sum[0] += p[0];
        sum[1] += p[1];
    }
    *reinterpret_cast<f32x2*>(out + (size_t)(row_base + row) * NCLS + col2) = sum;
}

extern "C" void kernel_launch(void* const* d_in, const int* in_sizes, int n_in,
                              void* d_out, int out_size, void* d_ws, size_t ws_size,
                              hipStream_t stream) {
    const float* x      = (const float*)d_in[0];
    const float* W      = (const float*)d_in[1];
    const float* b      = (const float*)d_in[2];
    const int*   starts = (const int*)d_in[3];
    float*       out    = (float*)d_out;

    const size_t wbytes = (size_t)NCLS * CDIM * sizeof(unsigned short);  // 512 KB
    if (ws_size >= wbytes) {
        unsigned short* Wfm = (unsigned short*)d_ws;
        convert_w_fragmajor<<<128, 256, 0, stream>>>(W, Wfm);
        dropblock_gemm_kernel<true><<<BROWS / MROWS, 512, 0, stream>>>(x, W, Wfm, b, starts, out);
    } else {
        dropblock_gemm_kernel<false><<<BROWS / MROWS, 512, 0, stream>>>(x, W, nullptr, b, starts, out);
    }
}

// Round 10
// 53.483 us; speedup vs baseline: 1.0022x; 1.0022x over previous
//
#include <hip/hip_runtime.h>
#include <stdint.h>

#define BROWS 16384
#define CDIM  4096
#define NCLS  64
#define BLKLEN 819u
#define NWAVES 8
#define MROWS 32                  // rows per block
#define CH 256                    // block K-step per chunk (floats)
#define NCHUNK (CDIM / CH)        // 16

typedef __attribute__((ext_vector_type(4))) float f32x4;
typedef __attribute__((ext_vector_type(8))) short s16x8;   // 8 bf16 - MFMA A/B frag

// fp32 -> bf16 bits, round-to-nearest-even
static __device__ __forceinline__ unsigned short f2bf(float f) {
    union { float f; unsigned u; } v; v.f = f;
    unsigned u = v.u;
    u += 0x7FFFu + ((u >> 16) & 1u);
    return (unsigned short)(u >> 16);
}

static __device__ __forceinline__ void gload_lds16(const void* g, void* l) {
    __builtin_amdgcn_global_load_lds(
        (const __attribute__((address_space(1))) unsigned int*)g,
        (__attribute__((address_space(3))) unsigned int*)l,
        16, 0, 0);
}

// One-time W relayout to FRAGMENT-MAJOR bf16:
// unit u = (kk*4 + t)*64 + lane (16B each) holds bf16x8 of
//   W[t*16 + (lane&15)][kk*32 + (lane>>4)*8 .. +8)
__global__ __launch_bounds__(256) void convert_w_fragmajor(const float* __restrict__ W,
                                                           unsigned short* __restrict__ Wfm) {
    const int u    = blockIdx.x * 256 + threadIdx.x;   // 0..32767
    const int lane = u & 63;
    const int t    = (u >> 6) & 3;
    const int kk   = u >> 8;
    const int row  = t * 16 + (lane & 15);
    const int col  = kk * 32 + (lane >> 4) * 8;
    const float* p = W + (size_t)row * CDIM + col;
    f32x4 a = *reinterpret_cast<const f32x4*>(p);
    f32x4 b = *reinterpret_cast<const f32x4*>(p + 4);
    s16x8 o;
    #pragma unroll
    for (int j = 0; j < 4; ++j) {
        o[j]     = (short)f2bf(a[j]);
        o[j + 4] = (short)f2bf(b[j]);
    }
    *reinterpret_cast<s16x8*>(Wfm + (size_t)u * 8) = o;
}

// Masked skinny GEMM: out[16384,64] = mask(x) @ W^T + b
// Block = 32 rows x 8 waves (512 thr). HYBRID split: wave wv -> row half
// rh=wv>>2 (16 rows) x K quarter kq=wv&3 (64 cols per chunk). Each stage
// instruction covers 4 rows x 256B contiguous (2x longer runs than r8).
// Wave-private double-buffered LDS (4KB x 2) + reg-prefetched W (8 frags,
// depth-1) + counted vmcnt; no main-loop barriers. Fully-masked stage units
// address-clamped (static instr count; ~19% less x traffic).
// LDS swizzle: physical granule p of row r holds logical granule p^r
// (involution, bits 4-7); reads XOR byte with (row&15)<<4 -> balanced banks.
template<bool PRECONV>
__global__ __launch_bounds__(512, 4) void dropblock_gemm_kernel(
    const float* __restrict__ x,
    const float* __restrict__ Wf,            // fp32 W (fallback)
    const unsigned short* __restrict__ Wfm,  // frag-major bf16 W
    const float* __restrict__ bias,
    const int* __restrict__ starts,
    float* __restrict__ out)
{
    __shared__ float lds[NWAVES][2][16][64]; // 64 KB; 8 KB private per wave
    const int tid  = threadIdx.x;
    const int lane = tid & 63;
    const int wv   = tid >> 6;
    const int rh   = wv >> 2;                // row half (0/1)
    const int kq   = wv & 3;                 // K quarter
    const int l16  = lane & 15;
    const int lg   = lane >> 4;              // 0..3
    const int row_base = blockIdx.x * MROWS;
    const int wrb  = row_base + rh * 16;     // this wave's first row

    const int s0 = starts[wrb + l16];
    // starts for this lane's STAGE rows r = i*4 + lg
    int sr[4];
    #pragma unroll
    for (int i = 0; i < 4; ++i) sr[i] = starts[wrb + i * 4 + lg];

    char* mybuf = (char*)&lds[wv][0][0][0];

    f32x4 acc[4];
    #pragma unroll
    for (int t = 0; t < 4; ++t) acc[t] = (f32x4){0.f, 0.f, 0.f, 0.f};

    // Stage chunk ch (this wave's 16 rows x 64 cols f32) into buffer b.
    // Dest linear 16B unit u = i*64+lane -> row r = i*4+lg, phys granule
    // p = lane&15. Source = logical granule p^r of row r (pre-swizzle).
    auto stage = [&](int ch, int b) {
        char* lb = mybuf + b * 4096;
        const int colbase = ch * CH + kq * 64;
        const char* gclamp = (const char*)x + ((size_t)wrb * CDIM + (size_t)colbase) * 4;
        #pragma unroll
        for (int i = 0; i < 4; ++i) {
            const int r = i * 4 + lg;
            const int q = (lane & 15) ^ r;            // logical granule (0..15)
            const int c0 = colbase + q * 4;           // first col of this unit
            const bool fullmask = (unsigned)(c0 - sr[i]) <= (BLKLEN - 4u);
            const char* gnorm = (const char*)x
                + ((size_t)(wrb + r) * CDIM + (size_t)colbase) * 4 + q * 16;
            const char* g = fullmask ? gclamp : gnorm;
            gload_lds16(g, lb + i * 1024);
        }
    };

    s16x8 wfr[2][8];                          // W frag double-buffer (8/chunk)
    auto loadW = [&](int ch, int b) {
        #pragma unroll
        for (int c = 0; c < 2; ++c) {
            const int kk = ch * 8 + kq * 2 + c;
            #pragma unroll
            for (int t = 0; t < 4; ++t)
                wfr[b][c * 4 + t] = *reinterpret_cast<const s16x8*>(
                    Wfm + ((size_t)((kk * 4 + t) * 64 + lane)) * 8);
        }
    };

    stage(0, 0);
    if (PRECONV) loadW(0, 0);

    #pragma unroll
    for (int ch = 0; ch < NCHUNK; ++ch) {
        const int b = ch & 1;

        if (ch + 1 < NCHUNK) {
            if (PRECONV) loadW(ch + 1, b ^ 1);
            stage(ch + 1, b ^ 1);
        }

        __builtin_amdgcn_sched_barrier(0);
        if (ch + 1 < NCHUNK) {
            if (PRECONV) asm volatile("s_waitcnt vmcnt(12)" ::: "memory"); // drain stage(ch)+W(ch)
            else         asm volatile("s_waitcnt vmcnt(4)"  ::: "memory"); // drain stage(ch)
        } else {
            asm volatile("s_waitcnt vmcnt(0)" ::: "memory");
        }
        __builtin_amdgcn_sched_barrier(0);

        const char* lb = mybuf + b * 4096;
        const unsigned swz = (unsigned)(l16 << 4);
        #pragma unroll
        for (int c = 0; c < 2; ++c) {
            const unsigned a0 = (unsigned)(l16 * 256 + lg * 32 + c * 128);
            f32x4 xa = *reinterpret_cast<const f32x4*>(lb + (a0 ^ swz));
            f32x4 xb = *reinterpret_cast<const f32x4*>(lb + ((a0 + 16) ^ swz));

            const int d0 = ch * CH + kq * 64 + c * 32 + lg * 8 - s0;
            s16x8 afrag;
            #pragma unroll
            for (int j = 0; j < 4; ++j) {
                float va = ((unsigned)(d0 + j)     >= BLKLEN) ? xa[j] : 0.f;
                float vb = ((unsigned)(d0 + 4 + j) >= BLKLEN) ? xb[j] : 0.f;
                afrag[j]     = (short)f2bf(va);
                afrag[j + 4] = (short)f2bf(vb);
            }

            #pragma unroll
            for (int t = 0; t < 4; ++t) {
                s16x8 bfrag;
                if (PRECONV) {
                    bfrag = wfr[b][c * 4 + t];
                } else {
                    const int kk = ch * 8 + kq * 2 + c;
                    const float* wrow = Wf + (size_t)(t * 16 + l16) * CDIM + kk * 32 + lg * 8;
                    f32x4 wa = *reinterpret_cast<const f32x4*>(wrow);
                    f32x4 wb2 = *reinterpret_cast<const f32x4*>(wrow + 4);
                    #pragma unroll
                    for (int j = 0; j < 4; ++j) {
                        bfrag[j]     = (short)f2bf(wa[j]);
                        bfrag[j + 4] = (short)f2bf(wb2[j]);
                    }
                }
                acc[t] = __builtin_amdgcn_mfma_f32_16x16x32_bf16(afrag, bfrag, acc[t], 0, 0, 0);
            }
        }
    }

    // Partials: plds aliases stage buffers -> barrier before write and before
    // the cross-wave read. C/D layout: col = lane&15, row = lg*4 + i.
    __syncthreads();
    float (*plds)[16][64] = reinterpret_cast<float (*)[16][64]>(&lds[0][0][0][0]); // 32 KB
    #pragma unroll
    for (int t = 0; t < 4; ++t)
        #pragma unroll
        for (int i = 0; i < 4; ++i)
            plds[wv][lg * 4 + i][t * 16 + l16] = acc[t][i];
    __syncthreads();

    // Reduce 4 K-quarter partials (within this row's half) + bias.
    // 512 threads x f32x4 = 2048 outputs.
    const int row  = tid >> 4;               // 0..31
    const int col4 = (tid & 15) * 4;         // 0,4,..,60
    const int rh2  = row >> 4;
    f32x4 sum = *reinterpret_cast<const f32x4*>(bias + col4);
    #pragma unroll
    for (int q = 0; q < 4; ++q)
        sum += *reinterpret_cast<const f32x4*>(&plds[rh2 * 4 + q][row & 15][col4]);
    *reinterpret_cast<f32x4*>(out + (size_t)(row_base + row) * NCLS + col4) = sum;
}

extern "C" void kernel_launch(void* const* d_in, const int* in_sizes, int n_in,
                              void* d_out, int out_size, void* d_ws, size_t ws_size,
                              hipStream_t stream) {
    const float* x      = (const float*)d_in[0];
    const float* W      = (const float*)d_in[1];
    const float* b      = (const float*)d_in[2];
    const int*   starts = (const int*)d_in[3];
    float*       out    = (float*)d_out;

    const size_t wbytes = (size_t)NCLS * CDIM * sizeof(unsigned short);  // 512 KB
    if (ws_size >= wbytes) {
        unsigned short* Wfm = (unsigned short*)d_ws;
        convert_w_fragmajor<<<128, 256, 0, stream>>>(W, Wfm);
        dropblock_gemm_kernel<true><<<BROWS / MROWS, 512, 0, stream>>>(x, W, Wfm, b, starts, out);
    } else {
        dropblock_gemm_kernel<false><<<BROWS / MROWS, 512, 0, stream>>>(x, W, nullptr, b, starts, out);
    }
}

// Round 11
// 50.295 us; speedup vs baseline: 1.0657x; 1.0634x over previous
//
#include <hip/hip_runtime.h>
#include <stdint.h>

#define BROWS 16384
#define CDIM  4096
#define NCLS  64
#define BLKLEN 819u
#define NWAVES 8
#define MROWS 32                  // rows per block
#define CH 256                    // block K-step per chunk (floats); wave slice = 32
#define NCHUNK (CDIM / CH)        // 16

typedef __attribute__((ext_vector_type(4))) float f32x4;
typedef __attribute__((ext_vector_type(8))) short s16x8;   // 8 bf16 - MFMA A/B frag

// fp32 -> bf16 bits, round-to-nearest-even
static __device__ __forceinline__ unsigned short f2bf(float f) {
    union { float f; unsigned u; } v; v.f = f;
    unsigned u = v.u;
    u += 0x7FFFu + ((u >> 16) & 1u);
    return (unsigned short)(u >> 16);
}

static __device__ __forceinline__ void gload_lds16(const void* g, void* l) {
    __builtin_amdgcn_global_load_lds(
        (const __attribute__((address_space(1))) unsigned int*)g,
        (__attribute__((address_space(3))) unsigned int*)l,
        16, 0, 0);
}

// One-time W relayout to FRAGMENT-MAJOR bf16:
// unit u = (kk*4 + t)*64 + lane (16B each) holds bf16x8 of
//   W[t*16 + (lane&15)][kk*32 + (lane>>4)*8 .. +8)
__global__ __launch_bounds__(256) void convert_w_fragmajor(const float* __restrict__ W,
                                                           unsigned short* __restrict__ Wfm) {
    const int u    = blockIdx.x * 256 + threadIdx.x;   // 0..32767
    const int lane = u & 63;
    const int t    = (u >> 6) & 3;
    const int kk   = u >> 8;
    const int row  = t * 16 + (lane & 15);
    const int col  = kk * 32 + (lane >> 4) * 8;
    const float* p = W + (size_t)row * CDIM + col;
    f32x4 a = *reinterpret_cast<const f32x4*>(p);
    f32x4 b = *reinterpret_cast<const f32x4*>(p + 4);
    s16x8 o;
    #pragma unroll
    for (int j = 0; j < 4; ++j) {
        o[j]     = (short)f2bf(a[j]);
        o[j + 4] = (short)f2bf(b[j]);
    }
    *reinterpret_cast<s16x8*>(Wfm + (size_t)u * 8) = o;
}

// Masked skinny GEMM: out[16384,64] = mask(x) @ W^T + b
// Block = 32 rows x 8 waves (512 thr), split-K. Wave-private double-buffered
// LDS staging + reg-prefetched W + counted vmcnt, no main-loop barriers.
// Stage lanes whose 16B unit is fully inside the masked window are
// address-CLAMPED to one shared line (instruction count stays static for the
// vmcnt discipline; ~19% less x HBM traffic; afrag cndmask zeroes by index).
template<bool PRECONV>
__global__ __launch_bounds__(512, 4) void dropblock_gemm_kernel(
    const float* __restrict__ x,
    const float* __restrict__ Wf,            // fp32 W (fallback)
    const unsigned short* __restrict__ Wfm,  // frag-major bf16 W
    const float* __restrict__ bias,
    const int* __restrict__ starts,
    float* __restrict__ out)
{
    __shared__ float lds[NWAVES][2][MROWS][32]; // 64 KB; 8 KB private per wave
    const int tid  = threadIdx.x;
    const int lane = tid & 63;
    const int wv   = tid >> 6;               // wave 0..7 -> K-slice
    const int l16  = lane & 15;
    const int lg   = lane >> 4;              // 0..3
    const int row_base = blockIdx.x * MROWS;

    const int s0 = starts[row_base + l16];
    const int s1 = starts[row_base + 16 + l16];
    // starts for this lane's STAGE rows r = i*8 + (lane>>3)
    int sr[4];
    #pragma unroll
    for (int i = 0; i < 4; ++i) sr[i] = starts[row_base + i * 8 + (lane >> 3)];

    const unsigned swzA = (unsigned)((l16 & 7) << 4);
    char* mybuf = (char*)&lds[wv][0][0][0];

    f32x4 acc[2][4];
    #pragma unroll
    for (int f = 0; f < 2; ++f)
        #pragma unroll
        for (int t = 0; t < 4; ++t) acc[f][t] = (f32x4){0.f, 0.f, 0.f, 0.f};

    // Stage chunk ch (this wave's 32x32 f32 subtile) into private buffer b.
    // LDS linear 16B unit u = i*64+lane -> row r = i*8+(lane>>3), slot lane&7;
    // source pre-swizzled by ((r&7)<<4) so reads XOR the same involution.
    auto stage = [&](int ch, int b) {
        char* lb = mybuf + b * 4096;
        const size_t colbase = (size_t)ch * CH + (size_t)wv * 32;
        const char* gclamp = (const char*)x + ((size_t)row_base * CDIM + colbase) * 4;
        #pragma unroll
        for (int i = 0; i < 4; ++i) {
            const int r = i * 8 + (lane >> 3);
            const unsigned wb = ((unsigned)((lane & 7) * 16)) ^ ((unsigned)((r & 7) << 4));
            // first col of this lane's 4-float unit:
            const int c0 = (int)colbase + (int)(wb >> 2);
            // fully masked iff [c0, c0+4) subset of [sr, sr+819)
            const bool fullmask = (unsigned)(c0 - sr[i]) <= (BLKLEN - 4u);
            const char* gnorm = (const char*)x
                + ((size_t)(row_base + r) * CDIM + colbase) * 4 + wb;
            const char* g = fullmask ? gclamp : gnorm;
            gload_lds16(g, lb + i * 1024);
        }
    };

    s16x8 wfr[2][4];                          // W frag double-buffer
    auto loadW = [&](int ch, int b) {
        const int kk = ch * 8 + wv;           // global k0/32 index for this wave
        #pragma unroll
        for (int t = 0; t < 4; ++t)
            wfr[b][t] = *reinterpret_cast<const s16x8*>(
                Wfm + ((size_t)((kk * 4 + t) * 64 + lane)) * 8);
    };

    stage(0, 0);
    if (PRECONV) loadW(0, 0);

    #pragma unroll
    for (int ch = 0; ch < NCHUNK; ++ch) {
        const int b = ch & 1;

        if (ch + 1 < NCHUNK) {
            if (PRECONV) loadW(ch + 1, b ^ 1);
            stage(ch + 1, b ^ 1);
        }

        __builtin_amdgcn_sched_barrier(0);
        if (ch + 1 < NCHUNK) {
            if (PRECONV) asm volatile("s_waitcnt vmcnt(8)" ::: "memory");  // drain stage(ch)+W(ch)
            else         asm volatile("s_waitcnt vmcnt(4)" ::: "memory");  // drain stage(ch)
        } else {
            asm volatile("s_waitcnt vmcnt(0)" ::: "memory");
        }
        __builtin_amdgcn_sched_barrier(0);

        const char* lb = mybuf + b * 4096;
        #pragma unroll
        for (int f = 0; f < 2; ++f) {
            const int row = f * 16 + l16;
            const unsigned a0 = (unsigned)(row * 128 + lg * 32);
            f32x4 xa = *reinterpret_cast<const f32x4*>(lb + (a0 ^ swzA));
            f32x4 xb = *reinterpret_cast<const f32x4*>(lb + ((a0 + 16) ^ swzA));

            const int d0 = ch * CH + wv * 32 + lg * 8 - (f ? s1 : s0);
            s16x8 afrag;
            #pragma unroll
            for (int j = 0; j < 4; ++j) {
                float va = ((unsigned)(d0 + j)     >= BLKLEN) ? xa[j] : 0.f;
                float vb = ((unsigned)(d0 + 4 + j) >= BLKLEN) ? xb[j] : 0.f;
                afrag[j]     = (short)f2bf(va);
                afrag[j + 4] = (short)f2bf(vb);
            }

            #pragma unroll
            for (int t = 0; t < 4; ++t) {
                s16x8 bfrag;
                if (PRECONV) {
                    bfrag = wfr[b][t];
                } else {
                    const int kk = ch * 8 + wv;
                    const float* wrow = Wf + (size_t)(t * 16 + l16) * CDIM + kk * 32 + lg * 8;
                    f32x4 wa = *reinterpret_cast<const f32x4*>(wrow);
                    f32x4 wb2 = *reinterpret_cast<const f32x4*>(wrow + 4);
                    #pragma unroll
                    for (int j = 0; j < 4; ++j) {
                        bfrag[j]     = (short)f2bf(wa[j]);
                        bfrag[j + 4] = (short)f2bf(wb2[j]);
                    }
                }
                acc[f][t] = __builtin_amdgcn_mfma_f32_16x16x32_bf16(afrag, bfrag, acc[f][t], 0, 0, 0);
            }
        }
    }

    // Partials: each wave writes its OWN 8KB region; barrier only before the
    // cross-wave read.
    float (*plds)[MROWS][64] = reinterpret_cast<float (*)[MROWS][64]>(&lds[0][0][0][0]); // 64 KB
    #pragma unroll
    for (int f = 0; f < 2; ++f)
        #pragma unroll
        for (int t = 0; t < 4; ++t)
            #pragma unroll
            for (int i = 0; i < 4; ++i)
                plds[wv][f * 16 + lg * 4 + i][t * 16 + l16] = acc[f][t][i];
    __syncthreads();

    // Reduce 8 partials + bias. 512 threads x f32x4 = 2048 outputs.
    const int row  = tid >> 4;               // 0..31
    const int col4 = (tid & 15) * 4;         // 0,4,..,60
    f32x4 sum = *reinterpret_cast<const f32x4*>(bias + col4);
    #pragma unroll
    for (int w = 0; w < NWAVES; ++w)
        sum += *reinterpret_cast<const f32x4*>(&plds[w][row][col4]);
    *reinterpret_cast<f32x4*>(out + (size_t)(row_base + row) * NCLS + col4) = sum;
}

extern "C" void kernel_launch(void* const* d_in, const int* in_sizes, int n_in,
                              void* d_out, int out_size, void* d_ws, size_t ws_size,
                              hipStream_t stream) {
    const float* x      = (const float*)d_in[0];
    const float* W      = (const float*)d_in[1];
    const float* b      = (const float*)d_in[2];
    const int*   starts = (const int*)d_in[3];
    float*       out    = (float*)d_out;

    const size_t wbytes = (size_t)NCLS * CDIM * sizeof(unsigned short);  // 512 KB
    if (ws_size >= wbytes) {
        unsigned short* Wfm = (unsigned short*)d_ws;
        convert_w_fragmajor<<<128, 256, 0, stream>>>(W, Wfm);
        dropblock_gemm_kernel<true><<<BROWS / MROWS, 512, 0, stream>>>(x, W, Wfm, b, starts, out);
    } else {
        dropblock_gemm_kernel<false><<<BROWS / MROWS, 512, 0, stream>>>(x, W, nullptr, b, starts, out);
    }
}